// Round 10
// baseline (26.140 us; speedup 1.0000x reference)
//
#include <hip/hip_runtime.h>
#include <hip/hip_bf16.h>

#define N_NODES   200000
#define N_PATCHES 256
#define TSTEPS    12
#define NHID      16
#define HORIZON   12
#define GDIM      192            // NHID * TSTEPS
#define IN_DIM    204            // GDIM + TSTEPS
#define NCHUNKS   6250           // N_NODES / 32 (exact)
#define K2_THREADS 768
#define K2_WAVES_TOTAL 3072      // 256 blocks x 12 waves
#define TBL_U4    6528           // 256*204*2 bytes / 16

typedef __attribute__((ext_vector_type(8)))  short        bf16x8;
typedef __attribute__((ext_vector_type(16))) float        f32x16;
typedef __attribute__((ext_vector_type(4)))  unsigned int u32x4;

// cold-path pack (K1 only)
__device__ __forceinline__ unsigned int pk2(float lo, float hi) {
    unsigned short l = __builtin_bit_cast(unsigned short, __float2bfloat16(lo));
    unsigned short h = __builtin_bit_cast(unsigned short, __float2bfloat16(hi));
    return ((unsigned int)h << 16) | (unsigned int)l;
}

// hot-path pack: single HW instruction, dst = {bf16(hi)<<16 | bf16(lo)}
__device__ __forceinline__ unsigned int cvtpk(float lo, float hi) {
    unsigned int r;
    asm("v_cvt_pk_bf16_f32 %0, %1, %2" : "=v"(r) : "v"(lo), "v"(hi));
    return r;
}

__device__ __forceinline__ bf16x8 frag_of(unsigned int a, unsigned int b,
                                          unsigned int c, unsigned int d) {
    u32x4 u; u[0] = a; u[1] = b; u[2] = c; u[3] = d;
    return __builtin_bit_cast(bf16x8, u);
}

__device__ __forceinline__ float bf16bits_lo(unsigned int w) {
    return __builtin_bit_cast(float, w << 16);
}
__device__ __forceinline__ float bf16bits_hi(unsigned int w) {
    return __builtin_bit_cast(float, w & 0xffff0000u);
}

// async global->LDS copy, 16B per lane (wave-uniform base + lane*16 dest)
__device__ __forceinline__ void gload_lds16(const uint4* g, uint4* l) {
    __builtin_amdgcn_global_load_lds(
        (const __attribute__((address_space(1))) unsigned int*)g,
        (__attribute__((address_space(3))) unsigned int*)l,
        16, 0, 0);
}

// Clamped weight fetch helpers (OOB -> 0)
__device__ __forceinline__ float ldW1f(const float* __restrict__ W1, int k, int j) {
    const bool ok = (k < TSTEPS) && (j < IN_DIM);
    const int  idx = ok ? ((GDIM + k) * IN_DIM + j) : 0;
    const float v = W1[idx];
    return ok ? v : 0.0f;
}
__device__ __forceinline__ float ldW2t(const float* __restrict__ W2, int j, int o) {
    const bool ok = (j < IN_DIM) && (o < HORIZON);
    const int  idx = ok ? (j * HORIZON + o) : 0;
    const float v = W2[idx];
    return ok ? v : 0.0f;
}

// ---------------------------------------------------------------------------
// Kernel 1 (grid 257 x 1024) — unchanged from R9 (proven):
//  blocks 0..255 : patch_hb[p][j] = bf16(b1[j] + sum_{i<192} x[p][i]*W1[i][j])
//  block 256     : pack per-lane MFMA weight fragments (stacked k-layout
//                  m(e,hi) = (e&3)+8*(e>>2)+4*hi) into wfrag.
// ---------------------------------------------------------------------------
__global__ __launch_bounds__(1024) void precompute(
    const float* __restrict__ mixer_x,   // (1,12,256,16)
    const float* __restrict__ W1,        // (204,204)
    const float* __restrict__ b1,        // (204)
    const float* __restrict__ W2,        // (204,12)
    unsigned short* __restrict__ patch_hb, // (256,204) bf16
    u32x4* __restrict__ wfrag)           // (20,64)
{
    const int blk = blockIdx.x;
    const int tid = threadIdx.x;

    if (blk == N_PATCHES) {
        const int lane = tid & 63;
        const int g    = tid >> 6;        // 0..15
        const int jl   = lane & 31;
        const int kb   = 4 * (lane >> 5);
        for (int f = g; f < 20; f += 16) {
            u32x4 u;
            if (f < 7) {
                const int j = f * 32 + jl;
                u[0] = pk2(ldW1f(W1, kb + 0,  j), ldW1f(W1, kb + 1,  j));
                u[1] = pk2(ldW1f(W1, kb + 2,  j), ldW1f(W1, kb + 3,  j));
                u[2] = pk2(ldW1f(W1, kb + 8,  j), ldW1f(W1, kb + 9,  j));
                u[3] = pk2(ldW1f(W1, kb + 10, j), ldW1f(W1, kb + 11, j));
            } else {
                const int j0 = (f - 7) * 16 + kb;
                u[0] = pk2(ldW2t(W2, j0 + 0,  jl), ldW2t(W2, j0 + 1,  jl));
                u[1] = pk2(ldW2t(W2, j0 + 2,  jl), ldW2t(W2, j0 + 3,  jl));
                u[2] = pk2(ldW2t(W2, j0 + 8,  jl), ldW2t(W2, j0 + 9,  jl));
                u[3] = pk2(ldW2t(W2, j0 + 10, jl), ldW2t(W2, j0 + 11, jl));
            }
            wfrag[f * 64 + lane] = u;
        }
        return;
    }

    __shared__ float xs[GDIM];
    __shared__ float partial[3 * IN_DIM];
    const int p = blk;
    const int j = tid & 255;
    const int q = tid >> 8;               // i-quarter 0..3

    if (tid < GDIM) {
        const int t = tid >> 4, f = tid & 15;
        xs[tid] = mixer_x[(t * N_PATCHES + p) * NHID + f];
    }
    __syncthreads();

    float acc = 0.0f;
    if (j < IN_DIM) {
        acc = (q == 0) ? b1[j] : 0.0f;
        const int ibase = q * 48;
#pragma unroll 16
        for (int i = 0; i < 48; ++i)
            acc = fmaf(xs[ibase + i], W1[(ibase + i) * IN_DIM + j], acc);
        if (q > 0) partial[(q - 1) * IN_DIM + j] = acc;
    }
    __syncthreads();
    if (q == 0 && j < IN_DIM) {
        const float v = acc + partial[j] + partial[IN_DIM + j] + partial[2 * IN_DIM + j];
        patch_hb[p * IN_DIM + j] =
            __builtin_bit_cast(unsigned short, __float2bfloat16(v));
    }
}

// ---------------------------------------------------------------------------
// Kernel 2 (grid 256 x 768, 104448 B LDS, 3 waves/SIMD): stage full bf16
// patch table into LDS (async global_load_lds), then per-wave MFMA over
// chunks of 32 consecutive nodes (flat index c = blk*12+wid, stride 3072).
// All hot-loop fp32->bf16 packs use v_cvt_pk_bf16_f32 (1 VALU op per dword).
// GEMM1 (swapped): h^T = W1f^T x F^T + PH (C-init from LDS)
// GEMM2 (swapped): out^T = sum_kt W2^T x h-tile, single accumulator.
// ---------------------------------------------------------------------------
__global__ __launch_bounds__(K2_THREADS) void node_mlp_mfma(
    const float* __restrict__ features,       // (200000,12)
    const int*   __restrict__ node_patch,     // (200000)
    const unsigned short* __restrict__ patch_hb, // (256,204) bf16
    const u32x4* __restrict__ wfrag,          // (20,64)
    const float* __restrict__ b2,             // (12)
    float* __restrict__ out)                  // (200000,12)
{
    __shared__ unsigned short smem[N_PATCHES * IN_DIM];   // 104448 B

    const int tid  = threadIdx.x;
    const int lane = tid & 63;
    const int wid  = tid >> 6;
    const int jl   = lane & 31;
    const int hi   = lane >> 5;

    // ---- first chunk's loads: issue before staging ------------------------
    int c = blockIdx.x * 12 + wid;                        // 0..3071
    float4 fa, fb, fc; int p;
    {
        const float4* fp = (const float4*)(features + (c * 32 + jl) * TSTEPS);
        fa = fp[0]; fb = fp[1]; fc = fp[2];
        p  = node_patch[c * 32 + jl];
    }

    bf16x8 A1f[7], A2f[13];
#pragma unroll
    for (int f = 0; f < 7; ++f)
        A1f[f] = __builtin_bit_cast(bf16x8, wfrag[f * 64 + lane]);
#pragma unroll
    for (int f = 0; f < 13; ++f)
        A2f[f] = __builtin_bit_cast(bf16x8, wfrag[(7 + f) * 64 + lane]);

    const float4 b2A = *(const float4*)(b2 + 4 * hi);     // b2[0..3] / b2[4..7]
    const float4 b2B = *(const float4*)(b2 + 8);          // b2[8..11] (hi0)

    // ---- async stage bf16 patch table -> LDS ------------------------------
    {
        const uint4* src = (const uint4*)patch_hb;
        uint4* dst = (uint4*)smem;
#pragma unroll
        for (int k = 0; k < 9; ++k) {
            const int i = tid + k * K2_THREADS;
            if (i < TBL_U4) gload_lds16(src + i, dst + i);
        }
    }
    __syncthreads();   // drains vmcnt (incl. global_load_lds) + lgkm

    // ---- chunk loop with depth-1 software pipeline ------------------------
    while (true) {
        const int  cn    = c + K2_WAVES_TOTAL;
        const bool haveN = (cn < NCHUNKS);
        float4 fa2, fb2, fc2; int p2 = 0;
        if (haveN) {                                      // prefetch next chunk
            const float4* fq = (const float4*)(features + (cn * 32 + jl) * TSTEPS);
            fa2 = fq[0]; fb2 = fq[1]; fc2 = fq[2];
            p2  = node_patch[cn * 32 + jl];
        }

        // B1: F^T[k][node], stacked layout (k>=12 -> 0), HW pack
        const bf16x8 B1 = frag_of(hi ? cvtpk(fb.x, fb.y) : cvtpk(fa.x, fa.y),
                                  hi ? cvtpk(fb.z, fb.w) : cvtpk(fa.z, fa.w),
                                  hi ? 0u                : cvtpk(fc.x, fc.y),
                                  hi ? 0u                : cvtpk(fc.z, fc.w));

        const unsigned short* row = smem + p * IN_DIM;

        f32x16 oacc;
#pragma unroll
        for (int e = 0; e < 16; ++e) oacc[e] = 0.0f;

#pragma unroll
        for (int t = 0; t < 7; ++t) {
            f32x16 acc;
#pragma unroll
            for (int G = 0; G < 4; ++G) {
                const int eoff = t * 32 + 8 * G + 4 * hi;
                const bool ok  = (eoff <= 200);           // eoff+3 <= 203
                const uint2 r  = *(const uint2*)(row + (ok ? eoff : 0));
                acc[4 * G + 0] = ok ? bf16bits_lo(r.x) : 0.0f;
                acc[4 * G + 1] = ok ? bf16bits_hi(r.x) : 0.0f;
                acc[4 * G + 2] = ok ? bf16bits_lo(r.y) : 0.0f;
                acc[4 * G + 3] = ok ? bf16bits_hi(r.y) : 0.0f;
            }

            acc = __builtin_amdgcn_mfma_f32_32x32x16_bf16(A1f[t], B1, acc, 0, 0, 0);

            // relu + HW pack: acc element order IS the B-operand element order
            const bf16x8 ba = frag_of(
                cvtpk(fmaxf(acc[0], 0.f), fmaxf(acc[1], 0.f)),
                cvtpk(fmaxf(acc[2], 0.f), fmaxf(acc[3], 0.f)),
                cvtpk(fmaxf(acc[4], 0.f), fmaxf(acc[5], 0.f)),
                cvtpk(fmaxf(acc[6], 0.f), fmaxf(acc[7], 0.f)));
            oacc = __builtin_amdgcn_mfma_f32_32x32x16_bf16(A2f[2 * t], ba, oacc, 0, 0, 0);

            if (t < 6) {
                const bf16x8 bb = frag_of(
                    cvtpk(fmaxf(acc[8],  0.f), fmaxf(acc[9],  0.f)),
                    cvtpk(fmaxf(acc[10], 0.f), fmaxf(acc[11], 0.f)),
                    cvtpk(fmaxf(acc[12], 0.f), fmaxf(acc[13], 0.f)),
                    cvtpk(fmaxf(acc[14], 0.f), fmaxf(acc[15], 0.f)));
                oacc = __builtin_amdgcn_mfma_f32_32x32x16_bf16(A2f[2 * t + 1], bb, oacc, 0, 0, 0);
            }
        }

        // ---- store: D row of elem e = (e&3)+8*(e>>2)+4*hi, col = node -----
        {
            const int node = c * 32 + jl;                 // always < N_NODES
            float* orow = out + node * HORIZON;
            if (hi == 0) {
                *(float4*)(orow + 0) = make_float4(oacc[0] + b2A.x, oacc[1] + b2A.y,
                                                   oacc[2] + b2A.z, oacc[3] + b2A.w);
                *(float4*)(orow + 8) = make_float4(oacc[4] + b2B.x, oacc[5] + b2B.y,
                                                   oacc[6] + b2B.z, oacc[7] + b2B.w);
            } else {
                *(float4*)(orow + 4) = make_float4(oacc[0] + b2A.x, oacc[1] + b2A.y,
                                                   oacc[2] + b2A.z, oacc[3] + b2A.w);
            }
        }

        if (!haveN) break;
        fa = fa2; fb = fb2; fc = fc2; p = p2; c = cn;
    }
}

// ---------------------------------------------------------------------------
extern "C" void kernel_launch(void* const* d_in, const int* in_sizes, int n_in,
                              void* d_out, int out_size, void* d_ws, size_t ws_size,
                              hipStream_t stream) {
    const float* mixer_x    = (const float*)d_in[0];
    const float* features   = (const float*)d_in[1];
    const float* W1         = (const float*)d_in[2];
    const float* b1         = (const float*)d_in[3];
    const float* W2         = (const float*)d_in[4];
    const float* b2         = (const float*)d_in[5];
    const int*   node_patch = (const int*)d_in[6];
    float* out = (float*)d_out;

    unsigned short* patch_hb = (unsigned short*)d_ws;          // 104448 B
    u32x4*          wfrag    = (u32x4*)((char*)d_ws + 104448); // +20480 B

    precompute<<<257, 1024, 0, stream>>>(mixer_x, W1, b1, W2, patch_hb, wfrag);

    node_mlp_mfma<<<256, K2_THREADS, 0, stream>>>(features, node_patch,
                                                  patch_hb, wfrag, b2, out);
}

// Round 11
// 25.057 us; speedup vs baseline: 1.0432x; 1.0432x over previous
//
#include <hip/hip_runtime.h>
#include <hip/hip_bf16.h>

#define N_NODES   200000
#define N_PATCHES 256
#define TSTEPS    12
#define NHID      16
#define HORIZON   12
#define GDIM      192            // NHID * TSTEPS
#define IN_DIM    204            // GDIM + TSTEPS
#define PH_STRIDE 206            // padded row: 103 dwords (odd -> uniform banks)
#define PH_STRIDE_DW 103
#define NCHUNKS   6250           // N_NODES / 32 (exact)
#define K2_THREADS 512
#define TOTAL_WAVES 2048         // 256 blocks x 8 waves
#define TBL_U4    6592           // 256*206*2 bytes / 16

typedef __attribute__((ext_vector_type(8)))  short        bf16x8;
typedef __attribute__((ext_vector_type(16))) float        f32x16;
typedef __attribute__((ext_vector_type(4)))  unsigned int u32x4;

// pack two fp32 -> one dword of 2 bf16 (compiler fuses to v_cvt_pk_bf16_f32)
__device__ __forceinline__ unsigned int pk2(float lo, float hi) {
    unsigned short l = __builtin_bit_cast(unsigned short, __float2bfloat16(lo));
    unsigned short h = __builtin_bit_cast(unsigned short, __float2bfloat16(hi));
    return ((unsigned int)h << 16) | (unsigned int)l;
}

__device__ __forceinline__ bf16x8 frag_of(unsigned int a, unsigned int b,
                                          unsigned int c, unsigned int d) {
    u32x4 u; u[0] = a; u[1] = b; u[2] = c; u[3] = d;
    return __builtin_bit_cast(bf16x8, u);
}

__device__ __forceinline__ float bf16bits_lo(unsigned int w) {
    return __builtin_bit_cast(float, w << 16);
}
__device__ __forceinline__ float bf16bits_hi(unsigned int w) {
    return __builtin_bit_cast(float, w & 0xffff0000u);
}

// async global->LDS copy, 16B per lane (wave-uniform base + lane*16 dest)
__device__ __forceinline__ void gload_lds16(const uint4* g, uint4* l) {
    __builtin_amdgcn_global_load_lds(
        (const __attribute__((address_space(1))) unsigned int*)g,
        (__attribute__((address_space(3))) unsigned int*)l,
        16, 0, 0);
}

// Clamped weight fetch helpers (OOB -> 0)
__device__ __forceinline__ float ldW1f(const float* __restrict__ W1, int k, int j) {
    const bool ok = (k < TSTEPS) && (j < IN_DIM);
    const int  idx = ok ? ((GDIM + k) * IN_DIM + j) : 0;
    const float v = W1[idx];
    return ok ? v : 0.0f;
}
__device__ __forceinline__ float ldW2t(const float* __restrict__ W2, int j, int o) {
    const bool ok = (j < IN_DIM) && (o < HORIZON);
    const int  idx = ok ? (j * HORIZON + o) : 0;
    const float v = W2[idx];
    return ok ? v : 0.0f;
}

// ---------------------------------------------------------------------------
// Kernel 1 (grid 257 x 1024) — R9 structure; only change: PH row stride 206.
// ---------------------------------------------------------------------------
__global__ __launch_bounds__(1024) void precompute(
    const float* __restrict__ mixer_x,   // (1,12,256,16)
    const float* __restrict__ W1,        // (204,204)
    const float* __restrict__ b1,        // (204)
    const float* __restrict__ W2,        // (204,12)
    unsigned short* __restrict__ patch_hb, // (256,206) bf16, cols 204/205 pad
    u32x4* __restrict__ wfrag)           // (20,64)
{
    const int blk = blockIdx.x;
    const int tid = threadIdx.x;

    if (blk == N_PATCHES) {
        const int lane = tid & 63;
        const int g    = tid >> 6;        // 0..15
        const int jl   = lane & 31;
        const int kb   = 4 * (lane >> 5);
        for (int f = g; f < 20; f += 16) {
            u32x4 u;
            if (f < 7) {
                const int j = f * 32 + jl;
                u[0] = pk2(ldW1f(W1, kb + 0,  j), ldW1f(W1, kb + 1,  j));
                u[1] = pk2(ldW1f(W1, kb + 2,  j), ldW1f(W1, kb + 3,  j));
                u[2] = pk2(ldW1f(W1, kb + 8,  j), ldW1f(W1, kb + 9,  j));
                u[3] = pk2(ldW1f(W1, kb + 10, j), ldW1f(W1, kb + 11, j));
            } else {
                const int j0 = (f - 7) * 16 + kb;
                u[0] = pk2(ldW2t(W2, j0 + 0,  jl), ldW2t(W2, j0 + 1,  jl));
                u[1] = pk2(ldW2t(W2, j0 + 2,  jl), ldW2t(W2, j0 + 3,  jl));
                u[2] = pk2(ldW2t(W2, j0 + 8,  jl), ldW2t(W2, j0 + 9,  jl));
                u[3] = pk2(ldW2t(W2, j0 + 10, jl), ldW2t(W2, j0 + 11, jl));
            }
            wfrag[f * 64 + lane] = u;
        }
        return;
    }

    __shared__ float xs[GDIM];
    __shared__ float partial[3 * IN_DIM];
    const int p = blk;
    const int j = tid & 255;
    const int q = tid >> 8;               // i-quarter 0..3

    if (tid < GDIM) {
        const int t = tid >> 4, f = tid & 15;
        xs[tid] = mixer_x[(t * N_PATCHES + p) * NHID + f];
    }
    __syncthreads();

    float acc = 0.0f;
    if (j < IN_DIM) {
        acc = (q == 0) ? b1[j] : 0.0f;
        const int ibase = q * 48;
#pragma unroll 16
        for (int i = 0; i < 48; ++i)
            acc = fmaf(xs[ibase + i], W1[(ibase + i) * IN_DIM + j], acc);
        if (q > 0) partial[(q - 1) * IN_DIM + j] = acc;
    }
    __syncthreads();
    if (q == 0 && j < IN_DIM) {
        const float v = acc + partial[j] + partial[IN_DIM + j] + partial[2 * IN_DIM + j];
        patch_hb[p * PH_STRIDE + j] =
            __builtin_bit_cast(unsigned short, __float2bfloat16(v));
    }
}

// ---------------------------------------------------------------------------
// Kernel 2 (grid 256 x 512, 105472 B LDS): async-stage bf16 patch table
// (stride-206 rows -> 103-dword stride, gcd(103,32)=1 -> uniform LDS banks),
// then per-wave MFMA over chunks of 32 consecutive nodes (c = blk*8+wid,
// stride 2048). C-init via ds_read_b32 pairs, PREFETCHED one tile ahead so
// LDS latency hides under MFMA+pack. Feature loads pipelined one chunk ahead.
// GEMM1 (swapped): h^T = W1f^T x F^T + PH;  GEMM2: out^T = sum W2^T x h-tile
// with even/odd split accumulators.
// ---------------------------------------------------------------------------
__global__ __launch_bounds__(K2_THREADS) void node_mlp_mfma(
    const float* __restrict__ features,       // (200000,12)
    const int*   __restrict__ node_patch,     // (200000)
    const unsigned short* __restrict__ patch_hb, // (256,206) bf16
    const u32x4* __restrict__ wfrag,          // (20,64)
    const float* __restrict__ b2,             // (12)
    float* __restrict__ out)                  // (200000,12)
{
    __shared__ unsigned short smem[N_PATCHES * PH_STRIDE];   // 105472 B

    const int tid  = threadIdx.x;
    const int lane = tid & 63;
    const int wid  = tid >> 6;
    const int jl   = lane & 31;
    const int hi   = lane >> 5;

    // ---- first chunk's loads: issue before staging ------------------------
    int c = blockIdx.x * 8 + wid;                         // 0..2047
    float4 fa, fb, fc; int p;
    {
        const float4* fp = (const float4*)(features + (c * 32 + jl) * TSTEPS);
        fa = fp[0]; fb = fp[1]; fc = fp[2];
        p  = node_patch[c * 32 + jl];
    }

    bf16x8 A1f[7], A2f[13];
#pragma unroll
    for (int f = 0; f < 7; ++f)
        A1f[f] = __builtin_bit_cast(bf16x8, wfrag[f * 64 + lane]);
#pragma unroll
    for (int f = 0; f < 13; ++f)
        A2f[f] = __builtin_bit_cast(bf16x8, wfrag[(7 + f) * 64 + lane]);

    const float4 b2A = *(const float4*)(b2 + 4 * hi);     // b2[0..3] / b2[4..7]
    const float4 b2B = *(const float4*)(b2 + 8);          // b2[8..11] (hi0)

    // ---- async stage bf16 patch table -> LDS ------------------------------
    {
        const uint4* src = (const uint4*)patch_hb;
        uint4* dst = (uint4*)smem;
#pragma unroll
        for (int k = 0; k < 13; ++k) {
            const int i = tid + k * K2_THREADS;
            if (i < TBL_U4) gload_lds16(src + i, dst + i);
        }
    }
    __syncthreads();   // drains vmcnt (incl. global_load_lds) + lgkm

    // ---- chunk loop --------------------------------------------------------
    while (true) {
        const int  cn    = c + TOTAL_WAVES;
        const bool haveN = (cn < NCHUNKS);
        float4 fa2, fb2, fc2; int p2 = 0;
        if (haveN) {                                      // prefetch next chunk
            const float4* fq = (const float4*)(features + (cn * 32 + jl) * TSTEPS);
            fa2 = fq[0]; fb2 = fq[1]; fc2 = fq[2];
            p2  = node_patch[cn * 32 + jl];
        }

        // B1: F^T[k][node], stacked layout (k>=12 -> 0)
        const bf16x8 B1 = frag_of(hi ? pk2(fb.x, fb.y) : pk2(fa.x, fa.y),
                                  hi ? pk2(fb.z, fb.w) : pk2(fa.z, fa.w),
                                  hi ? 0u              : pk2(fc.x, fc.y),
                                  hi ? 0u              : pk2(fc.z, fc.w));

        const unsigned int* dwrow =
            (const unsigned int*)smem + p * PH_STRIDE_DW;

        f32x16 oE, oO;
#pragma unroll
        for (int e = 0; e < 16; ++e) { oE[e] = 0.0f; oO[e] = 0.0f; }

        // tile-0 C-init loads (b32 pairs, uniform banks)
        unsigned int nx[8];
#pragma unroll
        for (int G = 0; G < 4; ++G) {
            const int di = 4 * G + 2 * hi;                // t=0 always valid
            nx[2 * G]     = dwrow[di];
            nx[2 * G + 1] = dwrow[di + 1];
        }

#pragma unroll
        for (int t = 0; t < 7; ++t) {
            unsigned int cu[8];
#pragma unroll
            for (int g = 0; g < 8; ++g) cu[g] = nx[g];

            if (t < 6) {                                  // prefetch tile t+1
#pragma unroll
                for (int G = 0; G < 4; ++G) {
                    const int e  = (t + 1) * 32 + 8 * G + 4 * hi;
                    const bool ok = (e <= 200);
                    const int di = ok ? (e >> 1) : 0;
                    nx[2 * G]     = dwrow[di];
                    nx[2 * G + 1] = dwrow[di + 1];
                }
            }

            f32x16 acc;
#pragma unroll
            for (int G = 0; G < 4; ++G) {
                const bool ok = (t * 32 + 8 * G + 4 * hi) <= 200;
                acc[4 * G + 0] = ok ? bf16bits_lo(cu[2 * G])     : 0.0f;
                acc[4 * G + 1] = ok ? bf16bits_hi(cu[2 * G])     : 0.0f;
                acc[4 * G + 2] = ok ? bf16bits_lo(cu[2 * G + 1]) : 0.0f;
                acc[4 * G + 3] = ok ? bf16bits_hi(cu[2 * G + 1]) : 0.0f;
            }

            acc = __builtin_amdgcn_mfma_f32_32x32x16_bf16(A1f[t], B1, acc, 0, 0, 0);

            // relu + pack: acc element order IS the B-operand element order
            const bf16x8 ba = frag_of(
                pk2(fmaxf(acc[0], 0.f), fmaxf(acc[1], 0.f)),
                pk2(fmaxf(acc[2], 0.f), fmaxf(acc[3], 0.f)),
                pk2(fmaxf(acc[4], 0.f), fmaxf(acc[5], 0.f)),
                pk2(fmaxf(acc[6], 0.f), fmaxf(acc[7], 0.f)));
            oE = __builtin_amdgcn_mfma_f32_32x32x16_bf16(A2f[2 * t], ba, oE, 0, 0, 0);

            if (t < 6) {
                const bf16x8 bb = frag_of(
                    pk2(fmaxf(acc[8],  0.f), fmaxf(acc[9],  0.f)),
                    pk2(fmaxf(acc[10], 0.f), fmaxf(acc[11], 0.f)),
                    pk2(fmaxf(acc[12], 0.f), fmaxf(acc[13], 0.f)),
                    pk2(fmaxf(acc[14], 0.f), fmaxf(acc[15], 0.f)));
                oO = __builtin_amdgcn_mfma_f32_32x32x16_bf16(A2f[2 * t + 1], bb, oO, 0, 0, 0);
            }
        }

        // ---- store: D row of elem e = (e&3)+8*(e>>2)+4*hi, col = node -----
        {
            const int node = c * 32 + jl;                 // always < N_NODES
            float* orow = out + node * HORIZON;
            const float s0 = oE[0] + oO[0], s1 = oE[1] + oO[1];
            const float s2 = oE[2] + oO[2], s3 = oE[3] + oO[3];
            if (hi == 0) {
                const float s4 = oE[4] + oO[4], s5 = oE[5] + oO[5];
                const float s6 = oE[6] + oO[6], s7 = oE[7] + oO[7];
                *(float4*)(orow + 0) = make_float4(s0 + b2A.x, s1 + b2A.y,
                                                   s2 + b2A.z, s3 + b2A.w);
                *(float4*)(orow + 8) = make_float4(s4 + b2B.x, s5 + b2B.y,
                                                   s6 + b2B.z, s7 + b2B.w);
            } else {
                *(float4*)(orow + 4) = make_float4(s0 + b2A.x, s1 + b2A.y,
                                                   s2 + b2A.z, s3 + b2A.w);
            }
        }

        if (!haveN) break;
        fa = fa2; fb = fb2; fc = fc2; p = p2; c = cn;
    }
}

// ---------------------------------------------------------------------------
extern "C" void kernel_launch(void* const* d_in, const int* in_sizes, int n_in,
                              void* d_out, int out_size, void* d_ws, size_t ws_size,
                              hipStream_t stream) {
    const float* mixer_x    = (const float*)d_in[0];
    const float* features   = (const float*)d_in[1];
    const float* W1         = (const float*)d_in[2];
    const float* b1         = (const float*)d_in[3];
    const float* W2         = (const float*)d_in[4];
    const float* b2         = (const float*)d_in[5];
    const int*   node_patch = (const int*)d_in[6];
    float* out = (float*)d_out;

    unsigned short* patch_hb = (unsigned short*)d_ws;          // 105472 B
    u32x4*          wfrag    = (u32x4*)((char*)d_ws + 105472); // +20480 B

    precompute<<<257, 1024, 0, stream>>>(mixer_x, W1, b1, W2, patch_hb, wfrag);

    node_mlp_mfma<<<256, K2_THREADS, 0, stream>>>(features, node_patch,
                                                  patch_hb, wfrag, b2, out);
}